// Round 7
// baseline (7171.175 us; speedup 1.0000x reference)
//
#include <hip/hip_runtime.h>

// ---------------------------------------------------------------------------
// LSTM scan, B=64 L=512 D=1024. Round 7 = Round 6 with the gemm_xproj LDS
// swizzle FIXED (was XOR over 3 bits for a 4-slot row -> read past the last
// __shared__ array => uninitialized LDS => NaN; root cause of R1 AND R6).
//   - R4-proven coherence protocol (ACQ_REL arrives, relaxed poll + one
//     agent acquire fence) with tree arrive (8 leaves x 8 + root 8).
//   - Variant A (ws permitting): x_proj precomputed by MFMA GEMM; scan's
//     x-part = 6B/thread scalar read. Variant B: R4 fused structure.
// ---------------------------------------------------------------------------

typedef float    f32x4 __attribute__((ext_vector_type(4)));
typedef _Float16 half8 __attribute__((ext_vector_type(8)));
typedef _Float16 half4 __attribute__((ext_vector_type(4)));

#define AS1 __attribute__((address_space(1)))
#define AS3 __attribute__((address_space(3)))

#define B_  64
#define L_  512
#define D_  1024
#define N3_ 3072

// ws layout (bytes)
#define WKT_OFF   0LL          // f16 [3072][1024]   6291456
#define WRT_OFF   6291456LL    // f16 [3072][1024]   6291456
#define XH_OFF    12582912LL   // f16 [B*L][1024]   67108864
#define H16_OFF   79691776LL   // f16 [2][64][1024]   262144
#define BAR_OFF   79953920LL   // unsigned[1024]        4096
#define XPROJ_OFF 79958016LL   // f16 [B*L][3072]   201326592  (variant A only)
#define NEED_A    (XPROJ_OFF + 201326592LL)

__device__ __forceinline__ float sigmoidf_fast(float x) {
  return __builtin_amdgcn_rcpf(1.f + __builtin_amdgcn_exp2f(-1.4426950408889634f * x));
}
__device__ __forceinline__ float tanhf_fast(float x) {
  return 1.f - 2.f * __builtin_amdgcn_rcpf(1.f + __builtin_amdgcn_exp2f(2.8853900817779268f * x));
}

// pinned (non-rematerializable) cached 16B load
#define ALOAD(dst, addr) \
  asm volatile("global_load_dwordx4 %0, %1, off" : "=v"(dst) : "v"(addr))
#define VMCNT0() asm volatile("s_waitcnt vmcnt(0)" ::: "memory")

__device__ __forceinline__ void gload_lds16(const void* g, void* l) {
  __builtin_amdgcn_global_load_lds((const AS1 unsigned int*)g,
                                   (AS3 unsigned int*)l, 16, 0, 0);
}

// ---------------- prep: transpose + f32->f16 (Wk and Wr) -------------------
__global__ __launch_bounds__(256) void transpose_f16(
    const float* __restrict__ Wk, const float* __restrict__ Wr,
    _Float16* __restrict__ WkT, _Float16* __restrict__ WrT)
{
  __shared__ float tile[32][33];
  int b = blockIdx.x;
  const float* in = Wk; _Float16* outp = WkT;
  if (b >= 3072) { b -= 3072; in = Wr; outp = WrT; }
  const int n0 = (b % 96) * 32;
  const int k0 = (b / 96) * 32;
  const int tx = threadIdx.x & 31, ty = threadIdx.x >> 5;
#pragma unroll
  for (int i = 0; i < 32; i += 8)
    tile[ty + i][tx] = in[(size_t)(k0 + ty + i) * N3_ + n0 + tx];
  __syncthreads();
#pragma unroll
  for (int i = 0; i < 32; i += 8)
    outp[(size_t)(n0 + ty + i) * D_ + k0 + tx] = (_Float16)tile[tx][ty + i];
}

// ---------------- prep: x -> f16, h0 -> BOTH h16 buffers -------------------
__global__ void convert_inputs(const f32x4* __restrict__ x, const f32x4* __restrict__ h0,
                               half4* __restrict__ xh, half4* __restrict__ h16a,
                               half4* __restrict__ h16b)
{
  const int NX = (B_ * L_ * D_) / 4;
  const int NH = (B_ * D_) / 4;
  for (int i = blockIdx.x * blockDim.x + threadIdx.x; i < NX + NH;
       i += gridDim.x * blockDim.x) {
    if (i < NX) {
      xh[i] = __builtin_convertvector(x[i], half4);
    } else {
      half4 v = __builtin_convertvector(h0[i - NX], half4);
      h16a[i - NX] = v;
      h16b[i - NX] = v;
    }
  }
}

// ---------------- variant A: x_proj GEMM (128x128 tile, BK=32) -------------
// LDS row = 32 f16 = FOUR 16B slots; swizzle XORs slot with (row&3) on both
// the (pre-swizzled) global source and the read -> bijective, in-bounds.
__global__ __launch_bounds__(256) void gemm_xproj(
    const _Float16* __restrict__ A,    // [32768][1024]
    const _Float16* __restrict__ BT,   // [3072][1024]
    _Float16* __restrict__ C)          // [32768][3072] f16
{
  __shared__ _Float16 As[128 * 32];
  __shared__ _Float16 Bs[128 * 32];
  const int tid = threadIdx.x, wave = tid >> 6, lane = tid & 63;
  const int mt = blockIdx.x / 24, ntile = blockIdx.x % 24;
  const int m0 = mt * 128, n0 = ntile * 128;
  const int l15 = lane & 15, l4h = lane >> 4;
  const int wm = (wave >> 1) * 64, wn = (wave & 1) * 64;

  const int c0i = wave * 2;
  const int lrow = lane >> 2;                       // 0..15 within chunk
  const int skel = 8 * ((lane & 3) ^ (lrow & 3));   // FIXED: 2-bit XOR, <32

  f32x4 acc[4][4];
#pragma unroll
  for (int i = 0; i < 4; ++i)
#pragma unroll
    for (int j = 0; j < 4; ++j) { f32x4 z = {0.f,0.f,0.f,0.f}; acc[i][j] = z; }

  for (int kk = 0; kk < 32; ++kk) {
    __syncthreads();
#pragma unroll
    for (int i = 0; i < 2; ++i) {
      const int c = c0i + i;
      const int row = c * 16 + lrow;
      gload_lds16(A  + (((size_t)(m0 + row)) << 10) + (kk << 5) + skel, &As[c << 9]);
      gload_lds16(BT + (((size_t)(n0 + row)) << 10) + (kk << 5) + skel, &Bs[c << 9]);
    }
    __syncthreads();
    half8 af[4], bf[4];
#pragma unroll
    for (int i = 0; i < 4; ++i) {
      const int ar = wm + i * 16 + l15;
      af[i] = *(const half8*)&As[(ar << 5) + ((l4h ^ (ar & 3)) << 3)];   // FIXED
      const int br = wn + i * 16 + l15;
      bf[i] = *(const half8*)&Bs[(br << 5) + ((l4h ^ (br & 3)) << 3)];   // FIXED
    }
#pragma unroll
    for (int i = 0; i < 4; ++i)
#pragma unroll
      for (int j = 0; j < 4; ++j)
        acc[i][j] = __builtin_amdgcn_mfma_f32_16x16x32_f16(af[i], bf[j], acc[i][j], 0, 0, 0);
  }
#pragma unroll
  for (int i = 0; i < 4; ++i) {
    const int row = m0 + wm + i * 16 + l4h * 4;
#pragma unroll
    for (int j = 0; j < 4; ++j) {
      const int col = n0 + wn + j * 16 + l15;
      _Float16* cp = C + (size_t)row * N3_ + col;
#pragma unroll
      for (int r = 0; r < 4; ++r)
        __builtin_nontemporal_store((_Float16)acc[i][j][r], cp + (size_t)r * N3_);
    }
  }
}

// ---------------- persistent scan (template over x-source) -----------------
// 256 WGs = 4 groups (b-tiles) x 64 d-slices; 4 waves own K-slices of 256.
// Tree arrive per group: 8 leaves (ord>>3) x 8 + root 8, all monotone.
template<bool FUSED_X>
__global__ __launch_bounds__(256, 1) void lstm_scan(
    const _Float16* __restrict__ WkT,   // [3072][1024]  (B only)
    const _Float16* __restrict__ WrT,   // [3072][1024]
    const _Float16* __restrict__ xh,    // [B*L][1024]   (B only)
    const _Float16* __restrict__ xproj, // [B*L][3072]   (A only)
    const float*    __restrict__ c0,    // [64][1024]
    float*          __restrict__ out,   // [64][512][1024]
    _Float16*       __restrict__ h16,   // [2][64][1024]
    unsigned*       __restrict__ bar)
{
  const int tid = threadIdx.x, wave = tid >> 6, lane = tid & 63;
  const int bid = blockIdx.x;
  const int grp = bid & 3;           // b-tile group (independent scan)
  const int ord = bid >> 2;          // d-slice 0..63
  const int b0 = grp * 16;
  const int d0 = ord * 16;
  const int l15 = lane & 15, l4h = lane >> 4;
  const int kbase = wave * 256;

  unsigned* const base  = bar + grp * 160;
  unsigned* const leafp = base + (ord >> 3) * 16;
  unsigned* const rootp = base + 128;
  unsigned* const flagp = base + 144;

  // ---- stationary weight fragments, pinned via asm loads ----
  half8 Wkf[3][8], Wrf[3][8];
#pragma unroll
  for (int g = 0; g < 3; ++g) {
    const _Float16* rr = WrT + (size_t)(g * D_ + d0 + l15) * D_ + kbase + l4h * 8;
#pragma unroll
    for (int kt = 0; kt < 8; ++kt) ALOAD(Wrf[g][kt], rr + kt * 32);
    if (FUSED_X) {
      const _Float16* kr = WkT + (size_t)(g * D_ + d0 + l15) * D_ + kbase + l4h * 8;
#pragma unroll
      for (int kt = 0; kt < 8; ++kt) ALOAD(Wkf[g][kt], kr + kt * 32);
    }
  }
  VMCNT0();

  const int rb = tid >> 4;   // batch within tile
  const int rd = tid & 15;   // d within tile
  float c = c0[(size_t)(b0 + rb) * D_ + d0 + rd];

  __shared__ float part[4][48][20];

  const _Float16* xrow = xh + ((size_t)(b0 + l15) * L_) * D_ + kbase + l4h * 8;
  const _Float16* xprow = xproj + ((size_t)(b0 + rb) * L_) * N3_ + d0 + rd;
  const size_t hoff   = (size_t)(b0 + l15) * D_ + kbase + l4h * 8;
  const size_t outidx = ((size_t)(b0 + rb) * L_) * D_ + d0 + rd;
  const size_t hidx   = (size_t)(b0 + rb) * D_ + d0 + rd;

  _Float16* hc = h16;            // h_t (both buffers pre-initialized with h0)
  _Float16* hn = h16 + B_ * D_;  // h_{t+1}

  f32x4 acc[3], acc2[3];
#pragma unroll
  for (int g = 0; g < 3; ++g) { f32x4 z = {0.f,0.f,0.f,0.f}; acc[g] = z; acc2[g] = z; }
  if (FUSED_X) {   // prologue: x-part for t=0
#pragma unroll
    for (int kt = 0; kt < 8; ++kt) {
      half8 afx = *(const half8*)(xrow + kt * 32);
#pragma unroll
      for (int g = 0; g < 3; ++g)
        acc[g] = __builtin_amdgcn_mfma_f32_16x16x32_f16(afx, Wkf[g][kt], acc[g], 0, 0, 0);
    }
  }

  for (int t = 0; t < L_; ++t) {
    // ---- per-step x biases (variant A): 3 scalar f16 loads ----
    float xf = 0.f, xo = 0.f, xg = 0.f;
    if (!FUSED_X) {
      const _Float16* xp = xprow + (size_t)t * N3_;
      xf = (float)xp[0];
      xo = (float)xp[D_];
      xg = (float)xp[2 * D_];
    }

    // ---- h fragments (plain loads; fresh due to last step's acquire) ----
    half8 af[8];
    const _Float16* hrow = hc + hoff;
#pragma unroll
    for (int kt = 0; kt < 8; ++kt) af[kt] = *(const half8*)(hrow + kt * 32);

#pragma unroll
    for (int kt = 0; kt < 8; ++kt)
#pragma unroll
      for (int g = 0; g < 3; ++g)
        acc[g] = __builtin_amdgcn_mfma_f32_16x16x32_f16(af[kt], Wrf[g][kt], acc[g], 0, 0, 0);

    // ---- cross-wave reduce via LDS ----
#pragma unroll
    for (int g = 0; g < 3; ++g)
      *(f32x4*)&part[wave][g * 16 + l15][l4h * 4] = acc[g];
    __syncthreads();

    float fv = xf, ov = xo, gv = xg;
#pragma unroll
    for (int w = 0; w < 4; ++w) {
      fv += part[w][rd][rb];
      ov += part[w][16 + rd][rb];
      gv += part[w][32 + rd][rb];
    }
    const float sf = sigmoidf_fast(fv);
    const float tg = tanhf_fast(gv);
    c = c * sf + (1.f - sf) * tg;
    const float h = sigmoidf_fast(ov) * tanhf_fast(c);

    out[outidx + (size_t)t * D_] = h;    // plain cached stores
    hn[hidx] = (_Float16)h;

    // ---- tree arrive: ACQ_REL RMWs are the release (R4-proven) ----
    __syncthreads();   // implicit vmcnt(0): all WG stores in L2
    if (tid == 0) {
      unsigned a = __hip_atomic_fetch_add(leafp, 1u, __ATOMIC_ACQ_REL,
                                          __HIP_MEMORY_SCOPE_AGENT);
      if (a == (unsigned)(8 * (t + 1) - 1)) {          // leaf closer
        unsigned r = __hip_atomic_fetch_add(rootp, 1u, __ATOMIC_ACQ_REL,
                                            __HIP_MEMORY_SCOPE_AGENT);
        if (r == (unsigned)(8 * (t + 1) - 1))          // root closer
          __hip_atomic_store(flagp, (unsigned)(t + 1), __ATOMIC_RELEASE,
                             __HIP_MEMORY_SCOPE_AGENT);
      }
    }

    // ---- barrier shadow (variant B): x-part MFMAs for step t+1 ----
    if (FUSED_X && t + 1 < L_) {
#pragma unroll
      for (int g = 0; g < 3; ++g) { f32x4 z = {0.f,0.f,0.f,0.f}; acc2[g] = z; }
      const _Float16* xr = xrow + (size_t)(t + 1) * D_;
#pragma unroll
      for (int kt = 0; kt < 8; ++kt) {
        half8 afx = *(const half8*)(xr + kt * 32);
#pragma unroll
        for (int g = 0; g < 3; ++g)
          acc2[g] = __builtin_amdgcn_mfma_f32_16x16x32_f16(afx, Wkf[g][kt], acc2[g], 0, 0, 0);
      }
    }
    __builtin_amdgcn_sched_barrier(0);

    // ---- wait: relaxed poll + ONE agent acquire fence (R4-proven) ----
    if (tid == 0) {
      while (__hip_atomic_load(flagp, __ATOMIC_RELAXED, __HIP_MEMORY_SCOPE_AGENT)
             < (unsigned)(t + 1)) {
        __builtin_amdgcn_s_sleep(1);
      }
      __builtin_amdgcn_fence(__ATOMIC_ACQUIRE, "agent");  // inv L1+L2 once
    }
    __syncthreads();

    if (FUSED_X) {
#pragma unroll
      for (int g = 0; g < 3; ++g) acc[g] = acc2[g];
    } else {
#pragma unroll
      for (int g = 0; g < 3; ++g) { f32x4 z = {0.f,0.f,0.f,0.f}; acc[g] = z; }
    }
    _Float16* tmp = hc; hc = hn; hn = tmp;
  }
}

// ---------------------------------------------------------------------------
extern "C" void kernel_launch(void* const* d_in, const int* in_sizes, int n_in,
                              void* d_out, int out_size, void* d_ws, size_t ws_size,
                              hipStream_t stream) {
  const float* x  = (const float*)d_in[0];
  const float* Wk = (const float*)d_in[1];
  const float* Wr = (const float*)d_in[2];
  const float* c0 = (const float*)d_in[3];
  const float* h0 = (const float*)d_in[4];
  float* out = (float*)d_out;

  char* ws = (char*)d_ws;
  _Float16* WkT   = (_Float16*)(ws + WKT_OFF);
  _Float16* WrT   = (_Float16*)(ws + WRT_OFF);
  _Float16* xh    = (_Float16*)(ws + XH_OFF);
  _Float16* h16   = (_Float16*)(ws + H16_OFF);
  unsigned* bar   = (unsigned*)(ws + BAR_OFF);
  _Float16* xproj = (_Float16*)(ws + XPROJ_OFF);

  hipMemsetAsync(bar, 0, 4096, stream);

  hipLaunchKernelGGL(transpose_f16, dim3(6144), dim3(256), 0, stream,
                     Wk, Wr, WkT, WrT);
  hipLaunchKernelGGL(convert_inputs, dim3(2048), dim3(256), 0, stream,
                     (const f32x4*)x, (const f32x4*)h0,
                     (half4*)xh, (half4*)h16, (half4*)(h16 + B_ * D_));

  if (ws_size >= (size_t)NEED_A) {
    hipLaunchKernelGGL(gemm_xproj, dim3(6144), dim3(256), 0, stream,
                       xh, WkT, xproj);
    void* kargs[8] = {(void*)&WkT, (void*)&WrT, (void*)&xh, (void*)&xproj,
                      (void*)&c0, (void*)&out, (void*)&h16, (void*)&bar};
    hipLaunchCooperativeKernel((void*)lstm_scan<false>, dim3(256), dim3(256),
                               kargs, 0, stream);
  } else {
    void* kargs[8] = {(void*)&WkT, (void*)&WrT, (void*)&xh, (void*)&xproj,
                      (void*)&c0, (void*)&out, (void*)&h16, (void*)&bar};
    hipLaunchCooperativeKernel((void*)lstm_scan<true>, dim3(256), dim3(256),
                               kargs, 0, stream);
  }
}